// Round 4
// baseline (332.899 us; speedup 1.0000x reference)
//
#include <hip/hip_runtime.h>
#include <math.h>

#define N_NODES 10000
#define N_EDGES 160000
#define CAP 64
#define GRID 768

#define NB_PROJ 628              // tasks 0..627   (157 node-tiles x 4 heads)
#define NB_SCORE 40              // tasks 628..667
#define NB_BUCKET 625            // tasks 668..1292
#define NTASK1 (NB_PROJ + NB_SCORE + NB_BUCKET)
#define NB_NODE 2500             // 4 nodes per task (one per wave)

typedef short bf16x8 __attribute__((ext_vector_type(8)));
typedef float f32x4 __attribute__((ext_vector_type(4)));

// ---------- helpers ----------
__device__ __forceinline__ float bf2f(unsigned short u) {
    return __uint_as_float(((unsigned int)u) << 16);
}
__device__ __forceinline__ unsigned short f2bf(float f) {
    unsigned int x = __float_as_uint(f);
    unsigned int r = (x + 0x7fffu + ((x >> 16) & 1u)) >> 16;   // RNE
    return (unsigned short)r;
}
__device__ __forceinline__ float softplus_f(float x) {
    return fmaxf(x, 0.f) + log1pf(expf(-fabsf(x)));
}

// ---------- sense-reversing grid barrier (persistent device globals; no reset) ----------
__device__ unsigned int g_cnt = 0;
__device__ unsigned int g_sense = 0;

__device__ __forceinline__ void gbar() {
    __syncthreads();   // all block stores drained (compiler emits vmcnt(0) before s_barrier)
    if (threadIdx.x == 0) {
        unsigned int e = __hip_atomic_load(&g_sense, __ATOMIC_ACQUIRE, __HIP_MEMORY_SCOPE_AGENT);
        unsigned int old = __hip_atomic_fetch_add(&g_cnt, 1, __ATOMIC_ACQ_REL, __HIP_MEMORY_SCOPE_AGENT);
        if (old == GRID - 1) {
            __hip_atomic_store(&g_cnt, 0, __ATOMIC_RELAXED, __HIP_MEMORY_SCOPE_AGENT);
            __hip_atomic_fetch_add(&g_sense, 1, __ATOMIC_RELEASE, __HIP_MEMORY_SCOPE_AGENT);
        } else {
            while (__hip_atomic_load(&g_sense, __ATOMIC_ACQUIRE, __HIP_MEMORY_SCOPE_AGENT) == e)
                __builtin_amdgcn_s_sleep(1);
        }
    }
    __syncthreads();
}

// ---------- the whole layer, one launch ----------
__global__ void __launch_bounds__(256, 4) k_fused(const float* __restrict__ x,
                                                  const int* __restrict__ ei,
                                                  const float* __restrict__ el,
                                                  const float* __restrict__ wproj,
                                                  const float* __restrict__ wrad,
                                                  const float* __restrict__ wtan,
                                                  const float* __restrict__ rsc,
                                                  const float* __restrict__ tsc,
                                                  const float* __restrict__ rdls,
                                                  const float* __restrict__ tb,
                                                  const float* __restrict__ tw,
                                                  const float* __restrict__ wout,
                                                  unsigned short* __restrict__ radb,
                                                  unsigned short* __restrict__ tanb,
                                                  float* __restrict__ rs,
                                                  float* __restrict__ ts,
                                                  int* __restrict__ cur,
                                                  int2* __restrict__ sbuf,
                                                  float* __restrict__ out) {
    __shared__ __align__(16) char smem[26624];
    int b = blockIdx.x;
    int t = threadIdx.x;
    int wid = t >> 6, lane = t & 63;

    // ---- phase 0: zero bucket counters ----
    {
        int idx = b * 256 + t;
        if (idx < N_NODES) cur[idx] = 0;
    }
    gbar();

    // ---- phase 1: proj (MFMA) | scores | bucket, task-looped ----
    for (int task = b; task < NTASK1; task += GRID) {
        if (task < NB_PROJ) {
            unsigned short* wt0 = (unsigned short*)smem;          // rad: [g*72+f]
            unsigned short* wt1 = wt0 + 64 * 72;                  // tan
            int h = task & 3;
            int nb = (task >> 2) * 64;
            const float* wr = wrad + h * 4096;
            const float* wtp = wtan + h * 4096;
            for (int i = 0; i < 16; ++i) {
                int e = t + 256 * i;               // e = f*64 + g
                int f = e >> 6, g = e & 63;
                wt0[g * 72 + f] = f2bf(wr[e]);
                wt1[g * 72 + f] = f2bf(wtp[e]);
            }
            __syncthreads();

            int q = lane >> 4, l16 = lane & 15;
            int node = nb + wid * 16 + l16;
            int nrow = min(node, N_NODES - 1);

            bf16x8 bfr[2];
#pragma unroll
            for (int kc = 0; kc < 2; ++kc) {
                const float* xp = x + nrow * 64 + kc * 32 + q * 8;
                float4 v0 = ((const float4*)xp)[0];
                float4 v1 = ((const float4*)xp)[1];
                bf16x8 bv;
                bv[0] = (short)f2bf(v0.x); bv[1] = (short)f2bf(v0.y);
                bv[2] = (short)f2bf(v0.z); bv[3] = (short)f2bf(v0.w);
                bv[4] = (short)f2bf(v1.x); bv[5] = (short)f2bf(v1.y);
                bv[6] = (short)f2bf(v1.z); bv[7] = (short)f2bf(v1.w);
                bfr[kc] = bv;
            }
#pragma unroll
            for (int gt = 0; gt < 4; ++gt) {
                f32x4 accr = {0.f, 0.f, 0.f, 0.f};
                f32x4 acct = {0.f, 0.f, 0.f, 0.f};
                int arow = gt * 16 + l16;
#pragma unroll
                for (int kc = 0; kc < 2; ++kc) {
                    bf16x8 ar = *(const bf16x8*)&wt0[arow * 72 + kc * 32 + q * 8];
                    bf16x8 at = *(const bf16x8*)&wt1[arow * 72 + kc * 32 + q * 8];
                    accr = __builtin_amdgcn_mfma_f32_16x16x32_bf16(ar, bfr[kc], accr, 0, 0, 0);
                    acct = __builtin_amdgcn_mfma_f32_16x16x32_bf16(at, bfr[kc], acct, 0, 0, 0);
                }
                if (node < N_NODES) {
                    int g = gt * 16 + q * 4;
                    ushort4 rv = make_ushort4(f2bf(accr[0]), f2bf(accr[1]),
                                              f2bf(accr[2]), f2bf(accr[3]));
                    ushort4 tv = make_ushort4(f2bf(acct[0]), f2bf(acct[1]),
                                              f2bf(acct[2]), f2bf(acct[3]));
                    *(ushort4*)(radb + node * 256 + h * 64 + g) = rv;
                    *(ushort4*)(tanb + node * 256 + h * 64 + g) = tv;
                }
            }
            __syncthreads();   // smem safe before any next task
        } else if (task < NB_PROJ + NB_SCORE) {
            float* vrl = (float*)smem;            // 256 floats
            float* vtl = vrl + 256;
            {
                int h = t >> 6, f = t & 63;
                const float* wrow = wproj + h * 4096 + f * 64;
                const float* rsp = rsc + h * 64;
                const float* tsp = tsc + h * 64;
                float ar = 0.f, at = 0.f;
                for (int g = 0; g < 64; ++g) {
                    float w = wrow[g];
                    ar += w * rsp[g];
                    at += w * tsp[g];
                }
                vrl[t] = ar;
                vtl[t] = at;
            }
            __syncthreads();
            int n = (task - NB_PROJ) * 256 + t;
            if (n < N_NODES) {
                const float4* xr = (const float4*)(x + n * 64);
                float accr[4] = {0.f, 0.f, 0.f, 0.f};
                float acct[4] = {0.f, 0.f, 0.f, 0.f};
                for (int i = 0; i < 16; ++i) {
                    float4 xv = xr[i];
#pragma unroll
                    for (int h = 0; h < 4; ++h) {
                        float4 a = ((const float4*)vrl)[h * 16 + i];
                        accr[h] += xv.x * a.x + xv.y * a.y + xv.z * a.z + xv.w * a.w;
                        float4 bb = ((const float4*)vtl)[h * 16 + i];
                        acct[h] += xv.x * bb.x + xv.y * bb.y + xv.z * bb.z + xv.w * bb.w;
                    }
                }
                ((float4*)rs)[n] = make_float4(accr[0], accr[1], accr[2], accr[3]);
                ((float4*)ts)[n] = make_float4(acct[0], acct[1], acct[2], acct[3]);
            }
            __syncthreads();
        } else {
            int e = (task - NB_PROJ - NB_SCORE) * 256 + t;
            if (e < N_EDGES) {
                int s = ei[e];
                int r = ei[N_EDGES + e];
                float len = el[e];
                int pos = atomicAdd(&cur[r], 1);
                if (pos < CAP) sbuf[r * CAP + pos] = make_int2(s, __float_as_int(len));
            }
        }
    }
    gbar();

    // ---- phase 2: per-node softmax + aggregation + output GEMM ----
    float* wl = (float*)smem;                         // 16384 B
    float* aldsb = (float*)(smem + 16384);            // 4*64*8 floats = 8192 B
    int*   sldsb = (int*)(smem + 24576);              // 4*64 ints = 1024 B
    float* preb = (float*)(smem + 25600);             // 4*64 floats = 1024 B
    for (int i = 0; i < 16; ++i) wl[t + 256 * i] = wout[t + 256 * i];
    __syncthreads();

    float scale = softplus_f(rdls[0]);
    float tb0 = tb[0], tb1 = tb[1], tb2 = tb[2], tb3 = tb[3];
    float tw0 = tw[0], tw1 = tw[1], tw2 = tw[2], tw3 = tw[3];
    float* alds = aldsb + wid * CAP * 8;
    int*   slds = sldsb + wid * CAP;
    float* prelds = preb + wid * 64;

    for (int nt = b; nt < NB_NODE; nt += GRID) {
        int n = nt * 4 + wid;
        int deg = min(cur[n], CAP);

        float4 rsr = ((const float4*)rs)[n];
        float4 tsr = ((const float4*)ts)[n];

        const float NEG = -3.402823466e38f;
        float rl0 = NEG, rl1 = NEG, rl2 = NEG, rl3 = NEG;
        float tl0 = NEG, tl1 = NEG, tl2 = NEG, tl3 = NEG;
        int s_e = 0;
        if (lane < deg) {
            int2 sl = sbuf[n * CAP + lane];
            s_e = sl.x;
            float len = __int_as_float(sl.y);
            float4 rss = ((const float4*)rs)[s_e];
            float4 tss = ((const float4*)ts)[s_e];
            float sl0 = scale * len;
            float i0 = 1.f / (softplus_f(tb0 + tw0 * len) + 1e-4f);
            float i1 = 1.f / (softplus_f(tb1 + tw1 * len) + 1e-4f);
            float i2 = 1.f / (softplus_f(tb2 + tw2 * len) + 1e-4f);
            float i3 = 1.f / (softplus_f(tb3 + tw3 * len) + 1e-4f);
            rl0 = ((rss.x - rsr.x) - sl0) * i0;
            rl1 = ((rss.y - rsr.y) - sl0) * i1;
            rl2 = ((rss.z - rsr.z) - sl0) * i2;
            rl3 = ((rss.w - rsr.w) - sl0) * i3;
            tl0 = tss.x - tsr.x;
            tl1 = tss.y - tsr.y;
            tl2 = tss.z - tsr.z;
            tl3 = tss.w - tsr.w;
        }
        float mr0 = rl0, mr1 = rl1, mr2 = rl2, mr3 = rl3;
        float mt0 = tl0, mt1 = tl1, mt2 = tl2, mt3 = tl3;
#pragma unroll
        for (int d = 32; d >= 1; d >>= 1) {
            mr0 = fmaxf(mr0, __shfl_xor(mr0, d)); mr1 = fmaxf(mr1, __shfl_xor(mr1, d));
            mr2 = fmaxf(mr2, __shfl_xor(mr2, d)); mr3 = fmaxf(mr3, __shfl_xor(mr3, d));
            mt0 = fmaxf(mt0, __shfl_xor(mt0, d)); mt1 = fmaxf(mt1, __shfl_xor(mt1, d));
            mt2 = fmaxf(mt2, __shfl_xor(mt2, d)); mt3 = fmaxf(mt3, __shfl_xor(mt3, d));
        }
        float er0 = 0.f, er1 = 0.f, er2 = 0.f, er3 = 0.f;
        float et0 = 0.f, et1 = 0.f, et2 = 0.f, et3 = 0.f;
        if (lane < deg) {
            er0 = expf(rl0 - mr0); er1 = expf(rl1 - mr1);
            er2 = expf(rl2 - mr2); er3 = expf(rl3 - mr3);
            et0 = expf(tl0 - mt0); et1 = expf(tl1 - mt1);
            et2 = expf(tl2 - mt2); et3 = expf(tl3 - mt3);
        }
        float sr0 = er0, sr1 = er1, sr2 = er2, sr3 = er3;
        float st0 = et0, st1 = et1, st2 = et2, st3 = et3;
#pragma unroll
        for (int d = 32; d >= 1; d >>= 1) {
            sr0 += __shfl_xor(sr0, d); sr1 += __shfl_xor(sr1, d);
            sr2 += __shfl_xor(sr2, d); sr3 += __shfl_xor(sr3, d);
            st0 += __shfl_xor(st0, d); st1 += __shfl_xor(st1, d);
            st2 += __shfl_xor(st2, d); st3 += __shfl_xor(st3, d);
        }
        if (lane < deg) {
            float* ap = alds + lane * 8;
            ((float4*)ap)[0] = make_float4(er0 / sr0, er1 / sr1, er2 / sr2, er3 / sr3);
            ((float4*)ap)[1] = make_float4(et0 / st0, et1 / st1, et2 / st2, et3 / st3);
            slds[lane] = s_e;
        }

        int h = lane >> 4;
        int hb = h * 64 + ((lane & 15) << 2);
        float a0 = 0.f, a1 = 0.f, a2 = 0.f, a3 = 0.f;
        float b0 = 0.f, b1 = 0.f, b2 = 0.f, b3 = 0.f;
        int i = 0;
        for (; i + 2 <= deg; i += 2) {
            int s0 = slds[i], s1 = slds[i + 1];
            float ar0 = alds[i * 8 + h],       at0 = alds[i * 8 + 4 + h];
            float ar1 = alds[(i + 1) * 8 + h], at1 = alds[(i + 1) * 8 + 4 + h];
            ushort4 rv0 = *(const ushort4*)(radb + s0 * 256 + hb);
            ushort4 tv0 = *(const ushort4*)(tanb + s0 * 256 + hb);
            ushort4 rv1 = *(const ushort4*)(radb + s1 * 256 + hb);
            ushort4 tv1 = *(const ushort4*)(tanb + s1 * 256 + hb);
            a0 += ar0 * bf2f(rv0.x) + ar1 * bf2f(rv1.x);
            a1 += ar0 * bf2f(rv0.y) + ar1 * bf2f(rv1.y);
            a2 += ar0 * bf2f(rv0.z) + ar1 * bf2f(rv1.z);
            a3 += ar0 * bf2f(rv0.w) + ar1 * bf2f(rv1.w);
            b0 += at0 * bf2f(tv0.x) + at1 * bf2f(tv1.x);
            b1 += at0 * bf2f(tv0.y) + at1 * bf2f(tv1.y);
            b2 += at0 * bf2f(tv0.z) + at1 * bf2f(tv1.z);
            b3 += at0 * bf2f(tv0.w) + at1 * bf2f(tv1.w);
        }
        if (i < deg) {
            int s0 = slds[i];
            float ar0 = alds[i * 8 + h], at0 = alds[i * 8 + 4 + h];
            ushort4 rv0 = *(const ushort4*)(radb + s0 * 256 + hb);
            ushort4 tv0 = *(const ushort4*)(tanb + s0 * 256 + hb);
            a0 += ar0 * bf2f(rv0.x); a1 += ar0 * bf2f(rv0.y);
            a2 += ar0 * bf2f(rv0.z); a3 += ar0 * bf2f(rv0.w);
            b0 += at0 * bf2f(tv0.x); b1 += at0 * bf2f(tv0.y);
            b2 += at0 * bf2f(tv0.z); b3 += at0 * bf2f(tv0.w);
        }
        if (deg > 0) {   // subtract receiver term: sum(alpha)==1
            ushort4 rv = *(const ushort4*)(radb + n * 256 + hb);
            ushort4 tv = *(const ushort4*)(tanb + n * 256 + hb);
            a0 -= bf2f(rv.x); a1 -= bf2f(rv.y); a2 -= bf2f(rv.z); a3 -= bf2f(rv.w);
            b0 -= bf2f(tv.x); b1 -= bf2f(tv.y); b2 -= bf2f(tv.z); b3 -= bf2f(tv.w);
        }
        float c0 = a0 + b0, c1 = a1 + b1, c2 = a2 + b2, c3 = a3 + b3;
        c0 += __shfl_xor(c0, 16); c0 += __shfl_xor(c0, 32);
        c1 += __shfl_xor(c1, 16); c1 += __shfl_xor(c1, 32);
        c2 += __shfl_xor(c2, 16); c2 += __shfl_xor(c2, 32);
        c3 += __shfl_xor(c3, 16); c3 += __shfl_xor(c3, 32);
        if (lane < 16) {
            ((float4*)prelds)[lane] =
                make_float4(c0 * 0.25f, c1 * 0.25f, c2 * 0.25f, c3 * 0.25f);
        }
        // prelds written/read by the same wave; no barrier needed

        float acc = 0.f;
#pragma unroll 4
        for (int gc = 0; gc < 16; ++gc) {
            float4 pv = ((const float4*)prelds)[gc];
            acc += pv.x * wl[(4 * gc + 0) * 64 + lane];
            acc += pv.y * wl[(4 * gc + 1) * 64 + lane];
            acc += pv.z * wl[(4 * gc + 2) * 64 + lane];
            acc += pv.w * wl[(4 * gc + 3) * 64 + lane];
        }
        out[n * 64 + lane] = x[n * 64 + lane] + acc;
    }
}

extern "C" void kernel_launch(void* const* d_in, const int* in_sizes, int n_in,
                              void* d_out, int out_size, void* d_ws, size_t ws_size,
                              hipStream_t stream) {
    const float* x     = (const float*)d_in[0];
    const int*   ei    = (const int*)d_in[1];
    /* d_in[2] edge_vec unused by reference */
    const float* el    = (const float*)d_in[3];
    const float* wproj = (const float*)d_in[4];
    const float* wrad  = (const float*)d_in[5];
    const float* wtan  = (const float*)d_in[6];
    const float* rsc   = (const float*)d_in[7];
    const float* tsc   = (const float*)d_in[8];
    const float* rdls  = (const float*)d_in[9];
    const float* tb    = (const float*)d_in[10];
    const float* tw    = (const float*)d_in[11];
    const float* wout  = (const float*)d_in[12];
    float* out = (float*)d_out;

    char* w = (char*)d_ws;
    size_t o = 0;
    auto nxt = [&](size_t bytes) -> char* {
        char* p = w + o;
        o += (bytes + 255) & ~(size_t)255;
        return p;
    };
    unsigned short* radb = (unsigned short*)nxt((size_t)N_NODES * 256 * 2);
    unsigned short* tanb = (unsigned short*)nxt((size_t)N_NODES * 256 * 2);
    float* rs = (float*)nxt((size_t)N_NODES * 4 * 4);
    float* ts = (float*)nxt((size_t)N_NODES * 4 * 4);
    int*   cur = (int*)nxt((size_t)N_NODES * 4);
    int2*  sbuf = (int2*)nxt((size_t)N_NODES * CAP * 8);

    k_fused<<<GRID, 256, 0, stream>>>(x, ei, el, wproj, wrad, wtan, rsc, tsc,
                                      rdls, tb, tw, wout,
                                      radb, tanb, rs, ts, cur, sbuf, out);
}

// Round 5
// 264.631 us; speedup vs baseline: 1.2580x; 1.2580x over previous
//
#include <hip/hip_runtime.h>
#include <math.h>

#define N_NODES 10000
#define N_EDGES 160000
#define CAP 64
#define GRID 768

#define NB_PROJ 628              // tasks 0..627   (157 node-tiles x 4 heads)
#define NB_SCORE 40              // tasks 628..667
#define NB_BUCKET 625            // tasks 668..1292
#define NTASK1 (NB_PROJ + NB_SCORE + NB_BUCKET)
#define NB_NODE 2500             // 4 nodes per task (one per wave)

typedef short bf16x8 __attribute__((ext_vector_type(8)));
typedef float f32x4 __attribute__((ext_vector_type(4)));

// ---------- helpers ----------
__device__ __forceinline__ float bf2f(unsigned short u) {
    return __uint_as_float(((unsigned int)u) << 16);
}
__device__ __forceinline__ unsigned short f2bf(float f) {
    unsigned int x = __float_as_uint(f);
    unsigned int r = (x + 0x7fffu + ((x >> 16) & 1u)) >> 16;   // RNE
    return (unsigned short)r;
}
__device__ __forceinline__ float softplus_f(float x) {
    return fmaxf(x, 0.f) + log1pf(expf(-fabsf(x)));
}

// ---------- sense-reversing grid barrier (persistent device globals; no reset) ----------
// R5 fix: RELAXED polls (no per-poll L2 inv), one release folded into arrival RMW,
// one acquire fence after wakeup. R4's ACQUIRE-in-poll caused per-poll buffer_inv
// -> L2 thrash -> 270us kernel.
__device__ unsigned int g_cnt = 0;
__device__ unsigned int g_sense = 0;

__device__ __forceinline__ void gbar() {
    __syncthreads();
    if (threadIdx.x == 0) {
        unsigned int e = __hip_atomic_load(&g_sense, __ATOMIC_RELAXED, __HIP_MEMORY_SCOPE_AGENT);
        // release this block's prior stores (one wbl2), then arrive
        unsigned int old = __hip_atomic_fetch_add(&g_cnt, 1, __ATOMIC_RELEASE, __HIP_MEMORY_SCOPE_AGENT);
        if (old == GRID - 1) {
            __hip_atomic_store(&g_cnt, 0, __ATOMIC_RELAXED, __HIP_MEMORY_SCOPE_AGENT);
            __hip_atomic_fetch_add(&g_sense, 1, __ATOMIC_RELEASE, __HIP_MEMORY_SCOPE_AGENT);
        } else {
            while (__hip_atomic_load(&g_sense, __ATOMIC_RELAXED, __HIP_MEMORY_SCOPE_AGENT) == e)
                __builtin_amdgcn_s_sleep(2);
        }
        // make remote releases visible: one L1/L2 invalidate
        __builtin_amdgcn_fence(__ATOMIC_ACQUIRE, "agent");
    }
    __syncthreads();
}

// ---------- the whole layer, one launch ----------
__global__ void __launch_bounds__(256, 4) k_fused(const float* __restrict__ x,
                                                  const int* __restrict__ ei,
                                                  const float* __restrict__ el,
                                                  const float* __restrict__ wproj,
                                                  const float* __restrict__ wrad,
                                                  const float* __restrict__ wtan,
                                                  const float* __restrict__ rsc,
                                                  const float* __restrict__ tsc,
                                                  const float* __restrict__ rdls,
                                                  const float* __restrict__ tb,
                                                  const float* __restrict__ tw,
                                                  const float* __restrict__ wout,
                                                  unsigned short* __restrict__ radb,
                                                  unsigned short* __restrict__ tanb,
                                                  float* __restrict__ rs,
                                                  float* __restrict__ ts,
                                                  int* __restrict__ cur,
                                                  int2* __restrict__ sbuf,
                                                  float* __restrict__ out) {
    __shared__ __align__(16) char smem[26624];
    int b = blockIdx.x;
    int t = threadIdx.x;
    int wid = t >> 6, lane = t & 63;

    // ---- phase 0: zero bucket counters ----
    {
        int idx = b * 256 + t;
        if (idx < N_NODES) cur[idx] = 0;
    }
    gbar();

    // ---- phase 1: proj (MFMA) | scores | bucket, task-looped ----
    for (int task = b; task < NTASK1; task += GRID) {
        if (task < NB_PROJ) {
            unsigned short* wt0 = (unsigned short*)smem;          // rad: [g*72+f]
            unsigned short* wt1 = wt0 + 64 * 72;                  // tan
            int h = task & 3;
            int nb = (task >> 2) * 64;
            const float* wr = wrad + h * 4096;
            const float* wtp = wtan + h * 4096;
            for (int i = 0; i < 16; ++i) {
                int e = t + 256 * i;               // e = f*64 + g
                int f = e >> 6, g = e & 63;
                wt0[g * 72 + f] = f2bf(wr[e]);
                wt1[g * 72 + f] = f2bf(wtp[e]);
            }
            __syncthreads();

            int q = lane >> 4, l16 = lane & 15;
            int node = nb + wid * 16 + l16;
            int nrow = min(node, N_NODES - 1);

            bf16x8 bfr[2];
#pragma unroll
            for (int kc = 0; kc < 2; ++kc) {
                const float* xp = x + nrow * 64 + kc * 32 + q * 8;
                float4 v0 = ((const float4*)xp)[0];
                float4 v1 = ((const float4*)xp)[1];
                bf16x8 bv;
                bv[0] = (short)f2bf(v0.x); bv[1] = (short)f2bf(v0.y);
                bv[2] = (short)f2bf(v0.z); bv[3] = (short)f2bf(v0.w);
                bv[4] = (short)f2bf(v1.x); bv[5] = (short)f2bf(v1.y);
                bv[6] = (short)f2bf(v1.z); bv[7] = (short)f2bf(v1.w);
                bfr[kc] = bv;
            }
#pragma unroll
            for (int gt = 0; gt < 4; ++gt) {
                f32x4 accr = {0.f, 0.f, 0.f, 0.f};
                f32x4 acct = {0.f, 0.f, 0.f, 0.f};
                int arow = gt * 16 + l16;
#pragma unroll
                for (int kc = 0; kc < 2; ++kc) {
                    bf16x8 ar = *(const bf16x8*)&wt0[arow * 72 + kc * 32 + q * 8];
                    bf16x8 at = *(const bf16x8*)&wt1[arow * 72 + kc * 32 + q * 8];
                    accr = __builtin_amdgcn_mfma_f32_16x16x32_bf16(ar, bfr[kc], accr, 0, 0, 0);
                    acct = __builtin_amdgcn_mfma_f32_16x16x32_bf16(at, bfr[kc], acct, 0, 0, 0);
                }
                if (node < N_NODES) {
                    int g = gt * 16 + q * 4;
                    ushort4 rv = make_ushort4(f2bf(accr[0]), f2bf(accr[1]),
                                              f2bf(accr[2]), f2bf(accr[3]));
                    ushort4 tv = make_ushort4(f2bf(acct[0]), f2bf(acct[1]),
                                              f2bf(acct[2]), f2bf(acct[3]));
                    *(ushort4*)(radb + node * 256 + h * 64 + g) = rv;
                    *(ushort4*)(tanb + node * 256 + h * 64 + g) = tv;
                }
            }
            __syncthreads();   // smem safe before any next task
        } else if (task < NB_PROJ + NB_SCORE) {
            float* vrl = (float*)smem;            // 256 floats
            float* vtl = vrl + 256;
            {
                int h = t >> 6, f = t & 63;
                const float* wrow = wproj + h * 4096 + f * 64;
                const float* rsp = rsc + h * 64;
                const float* tsp = tsc + h * 64;
                float ar = 0.f, at = 0.f;
                for (int g = 0; g < 64; ++g) {
                    float w = wrow[g];
                    ar += w * rsp[g];
                    at += w * tsp[g];
                }
                vrl[t] = ar;
                vtl[t] = at;
            }
            __syncthreads();
            int n = (task - NB_PROJ) * 256 + t;
            if (n < N_NODES) {
                const float4* xr = (const float4*)(x + n * 64);
                float accr[4] = {0.f, 0.f, 0.f, 0.f};
                float acct[4] = {0.f, 0.f, 0.f, 0.f};
                for (int i = 0; i < 16; ++i) {
                    float4 xv = xr[i];
#pragma unroll
                    for (int h = 0; h < 4; ++h) {
                        float4 a = ((const float4*)vrl)[h * 16 + i];
                        accr[h] += xv.x * a.x + xv.y * a.y + xv.z * a.z + xv.w * a.w;
                        float4 bb = ((const float4*)vtl)[h * 16 + i];
                        acct[h] += xv.x * bb.x + xv.y * bb.y + xv.z * bb.z + xv.w * bb.w;
                    }
                }
                ((float4*)rs)[n] = make_float4(accr[0], accr[1], accr[2], accr[3]);
                ((float4*)ts)[n] = make_float4(acct[0], acct[1], acct[2], acct[3]);
            }
            __syncthreads();
        } else {
            int e = (task - NB_PROJ - NB_SCORE) * 256 + t;
            if (e < N_EDGES) {
                int s = ei[e];
                int r = ei[N_EDGES + e];
                float len = el[e];
                int pos = atomicAdd(&cur[r], 1);
                if (pos < CAP) sbuf[r * CAP + pos] = make_int2(s, __float_as_int(len));
            }
        }
    }
    gbar();

    // ---- phase 2: per-node softmax + aggregation + output GEMM ----
    float* wl = (float*)smem;                         // 16384 B
    float* aldsb = (float*)(smem + 16384);            // 4*64*8 floats = 8192 B
    int*   sldsb = (int*)(smem + 24576);              // 4*64 ints = 1024 B
    float* preb = (float*)(smem + 25600);             // 4*64 floats = 1024 B
    for (int i = 0; i < 16; ++i) wl[t + 256 * i] = wout[t + 256 * i];
    __syncthreads();

    float scale = softplus_f(rdls[0]);
    float tb0 = tb[0], tb1 = tb[1], tb2 = tb[2], tb3 = tb[3];
    float tw0 = tw[0], tw1 = tw[1], tw2 = tw[2], tw3 = tw[3];
    float* alds = aldsb + wid * CAP * 8;
    int*   slds = sldsb + wid * CAP;
    float* prelds = preb + wid * 64;

    for (int nt = b; nt < NB_NODE; nt += GRID) {
        int n = nt * 4 + wid;
        int deg = min(cur[n], CAP);

        float4 rsr = ((const float4*)rs)[n];
        float4 tsr = ((const float4*)ts)[n];

        const float NEG = -3.402823466e38f;
        float rl0 = NEG, rl1 = NEG, rl2 = NEG, rl3 = NEG;
        float tl0 = NEG, tl1 = NEG, tl2 = NEG, tl3 = NEG;
        int s_e = 0;
        if (lane < deg) {
            int2 sl = sbuf[n * CAP + lane];
            s_e = sl.x;
            float len = __int_as_float(sl.y);
            float4 rss = ((const float4*)rs)[s_e];
            float4 tss = ((const float4*)ts)[s_e];
            float sl0 = scale * len;
            float i0 = 1.f / (softplus_f(tb0 + tw0 * len) + 1e-4f);
            float i1 = 1.f / (softplus_f(tb1 + tw1 * len) + 1e-4f);
            float i2 = 1.f / (softplus_f(tb2 + tw2 * len) + 1e-4f);
            float i3 = 1.f / (softplus_f(tb3 + tw3 * len) + 1e-4f);
            rl0 = ((rss.x - rsr.x) - sl0) * i0;
            rl1 = ((rss.y - rsr.y) - sl0) * i1;
            rl2 = ((rss.z - rsr.z) - sl0) * i2;
            rl3 = ((rss.w - rsr.w) - sl0) * i3;
            tl0 = tss.x - tsr.x;
            tl1 = tss.y - tsr.y;
            tl2 = tss.z - tsr.z;
            tl3 = tss.w - tsr.w;
        }
        float mr0 = rl0, mr1 = rl1, mr2 = rl2, mr3 = rl3;
        float mt0 = tl0, mt1 = tl1, mt2 = tl2, mt3 = tl3;
#pragma unroll
        for (int d = 32; d >= 1; d >>= 1) {
            mr0 = fmaxf(mr0, __shfl_xor(mr0, d)); mr1 = fmaxf(mr1, __shfl_xor(mr1, d));
            mr2 = fmaxf(mr2, __shfl_xor(mr2, d)); mr3 = fmaxf(mr3, __shfl_xor(mr3, d));
            mt0 = fmaxf(mt0, __shfl_xor(mt0, d)); mt1 = fmaxf(mt1, __shfl_xor(mt1, d));
            mt2 = fmaxf(mt2, __shfl_xor(mt2, d)); mt3 = fmaxf(mt3, __shfl_xor(mt3, d));
        }
        float er0 = 0.f, er1 = 0.f, er2 = 0.f, er3 = 0.f;
        float et0 = 0.f, et1 = 0.f, et2 = 0.f, et3 = 0.f;
        if (lane < deg) {
            er0 = expf(rl0 - mr0); er1 = expf(rl1 - mr1);
            er2 = expf(rl2 - mr2); er3 = expf(rl3 - mr3);
            et0 = expf(tl0 - mt0); et1 = expf(tl1 - mt1);
            et2 = expf(tl2 - mt2); et3 = expf(tl3 - mt3);
        }
        float sr0 = er0, sr1 = er1, sr2 = er2, sr3 = er3;
        float st0 = et0, st1 = et1, st2 = et2, st3 = et3;
#pragma unroll
        for (int d = 32; d >= 1; d >>= 1) {
            sr0 += __shfl_xor(sr0, d); sr1 += __shfl_xor(sr1, d);
            sr2 += __shfl_xor(sr2, d); sr3 += __shfl_xor(sr3, d);
            st0 += __shfl_xor(st0, d); st1 += __shfl_xor(st1, d);
            st2 += __shfl_xor(st2, d); st3 += __shfl_xor(st3, d);
        }
        if (lane < deg) {
            float* ap = alds + lane * 8;
            ((float4*)ap)[0] = make_float4(er0 / sr0, er1 / sr1, er2 / sr2, er3 / sr3);
            ((float4*)ap)[1] = make_float4(et0 / st0, et1 / st1, et2 / st2, et3 / st3);
            slds[lane] = s_e;
        }

        int h = lane >> 4;
        int hb = h * 64 + ((lane & 15) << 2);
        float a0 = 0.f, a1 = 0.f, a2 = 0.f, a3 = 0.f;
        float b0 = 0.f, b1 = 0.f, b2 = 0.f, b3 = 0.f;
        int i = 0;
        for (; i + 2 <= deg; i += 2) {
            int s0 = slds[i], s1 = slds[i + 1];
            float ar0 = alds[i * 8 + h],       at0 = alds[i * 8 + 4 + h];
            float ar1 = alds[(i + 1) * 8 + h], at1 = alds[(i + 1) * 8 + 4 + h];
            ushort4 rv0 = *(const ushort4*)(radb + s0 * 256 + hb);
            ushort4 tv0 = *(const ushort4*)(tanb + s0 * 256 + hb);
            ushort4 rv1 = *(const ushort4*)(radb + s1 * 256 + hb);
            ushort4 tv1 = *(const ushort4*)(tanb + s1 * 256 + hb);
            a0 += ar0 * bf2f(rv0.x) + ar1 * bf2f(rv1.x);
            a1 += ar0 * bf2f(rv0.y) + ar1 * bf2f(rv1.y);
            a2 += ar0 * bf2f(rv0.z) + ar1 * bf2f(rv1.z);
            a3 += ar0 * bf2f(rv0.w) + ar1 * bf2f(rv1.w);
            b0 += at0 * bf2f(tv0.x) + at1 * bf2f(tv1.x);
            b1 += at0 * bf2f(tv0.y) + at1 * bf2f(tv1.y);
            b2 += at0 * bf2f(tv0.z) + at1 * bf2f(tv1.z);
            b3 += at0 * bf2f(tv0.w) + at1 * bf2f(tv1.w);
        }
        if (i < deg) {
            int s0 = slds[i];
            float ar0 = alds[i * 8 + h], at0 = alds[i * 8 + 4 + h];
            ushort4 rv0 = *(const ushort4*)(radb + s0 * 256 + hb);
            ushort4 tv0 = *(const ushort4*)(tanb + s0 * 256 + hb);
            a0 += ar0 * bf2f(rv0.x); a1 += ar0 * bf2f(rv0.y);
            a2 += ar0 * bf2f(rv0.z); a3 += ar0 * bf2f(rv0.w);
            b0 += at0 * bf2f(tv0.x); b1 += at0 * bf2f(tv0.y);
            b2 += at0 * bf2f(tv0.z); b3 += at0 * bf2f(tv0.w);
        }
        if (deg > 0) {   // subtract receiver term: sum(alpha)==1
            ushort4 rv = *(const ushort4*)(radb + n * 256 + hb);
            ushort4 tv = *(const ushort4*)(tanb + n * 256 + hb);
            a0 -= bf2f(rv.x); a1 -= bf2f(rv.y); a2 -= bf2f(rv.z); a3 -= bf2f(rv.w);
            b0 -= bf2f(tv.x); b1 -= bf2f(tv.y); b2 -= bf2f(tv.z); b3 -= bf2f(tv.w);
        }
        float c0 = a0 + b0, c1 = a1 + b1, c2 = a2 + b2, c3 = a3 + b3;
        c0 += __shfl_xor(c0, 16); c0 += __shfl_xor(c0, 32);
        c1 += __shfl_xor(c1, 16); c1 += __shfl_xor(c1, 32);
        c2 += __shfl_xor(c2, 16); c2 += __shfl_xor(c2, 32);
        c3 += __shfl_xor(c3, 16); c3 += __shfl_xor(c3, 32);
        if (lane < 16) {
            ((float4*)prelds)[lane] =
                make_float4(c0 * 0.25f, c1 * 0.25f, c2 * 0.25f, c3 * 0.25f);
        }
        // prelds written/read by the same wave; no barrier needed

        float acc = 0.f;
#pragma unroll 4
        for (int gc = 0; gc < 16; ++gc) {
            float4 pv = ((const float4*)prelds)[gc];
            acc += pv.x * wl[(4 * gc + 0) * 64 + lane];
            acc += pv.y * wl[(4 * gc + 1) * 64 + lane];
            acc += pv.z * wl[(4 * gc + 2) * 64 + lane];
            acc += pv.w * wl[(4 * gc + 3) * 64 + lane];
        }
        out[n * 64 + lane] = x[n * 64 + lane] + acc;
    }
}

extern "C" void kernel_launch(void* const* d_in, const int* in_sizes, int n_in,
                              void* d_out, int out_size, void* d_ws, size_t ws_size,
                              hipStream_t stream) {
    const float* x     = (const float*)d_in[0];
    const int*   ei    = (const int*)d_in[1];
    /* d_in[2] edge_vec unused by reference */
    const float* el    = (const float*)d_in[3];
    const float* wproj = (const float*)d_in[4];
    const float* wrad  = (const float*)d_in[5];
    const float* wtan  = (const float*)d_in[6];
    const float* rsc   = (const float*)d_in[7];
    const float* tsc   = (const float*)d_in[8];
    const float* rdls  = (const float*)d_in[9];
    const float* tb    = (const float*)d_in[10];
    const float* tw    = (const float*)d_in[11];
    const float* wout  = (const float*)d_in[12];
    float* out = (float*)d_out;

    char* w = (char*)d_ws;
    size_t o = 0;
    auto nxt = [&](size_t bytes) -> char* {
        char* p = w + o;
        o += (bytes + 255) & ~(size_t)255;
        return p;
    };
    unsigned short* radb = (unsigned short*)nxt((size_t)N_NODES * 256 * 2);
    unsigned short* tanb = (unsigned short*)nxt((size_t)N_NODES * 256 * 2);
    float* rs = (float*)nxt((size_t)N_NODES * 4 * 4);
    float* ts = (float*)nxt((size_t)N_NODES * 4 * 4);
    int*   cur = (int*)nxt((size_t)N_NODES * 4);
    int2*  sbuf = (int2*)nxt((size_t)N_NODES * CAP * 8);

    k_fused<<<GRID, 256, 0, stream>>>(x, ei, el, wproj, wrad, wtan, rsc, tsc,
                                      rdls, tb, tw, wout,
                                      radb, tanb, rs, ts, cur, sbuf, out);
}

// Round 6
// 137.466 us; speedup vs baseline: 2.4217x; 1.9251x over previous
//
#include <hip/hip_runtime.h>
#include <math.h>

#define N_NODES 10000
#define N_EDGES 160000
#define CAP 64

// D1 task split
#define NB_SCORE 40
#define NB_BUCKET 625
#define NB_WPP 9
#define NB_D1 (NB_SCORE + NB_BUCKET + NB_WPP)

typedef short bf16x8 __attribute__((ext_vector_type(8)));
typedef float f32x4 __attribute__((ext_vector_type(4)));

// ---------- helpers ----------
__device__ __forceinline__ float bf2f(unsigned short u) {
    return __uint_as_float(((unsigned int)u) << 16);
}
__device__ __forceinline__ unsigned short f2bf(float f) {
    unsigned int x = __float_as_uint(f);
    unsigned int r = (x + 0x7fffu + ((x >> 16) & 1u)) >> 16;   // RNE
    return (unsigned short)r;
}
__device__ __forceinline__ float softplus_f(float x) {
    return fmaxf(x, 0.f) + log1pf(expf(-fabsf(x)));
}

// ---------- D1: scores | bucket | W'' precompute ----------
// W''_k = Wk @ Wout * 0.25 (k=0..3: Wr[h]; k=4..7: Wt[h]; k=8: -sum of all 8),
// stored TRANSPOSED: wppT[c*576 + k*64 + f] (bf16), c = out column.
__global__ void __launch_bounds__(256) k_prep(const float* __restrict__ x,
                                              const float* __restrict__ wproj,
                                              const float* __restrict__ wrad,
                                              const float* __restrict__ wtan,
                                              const float* __restrict__ rsc,
                                              const float* __restrict__ tsc,
                                              const float* __restrict__ wout,
                                              const int* __restrict__ ei,
                                              const float* __restrict__ el,
                                              float* __restrict__ rs,
                                              float* __restrict__ ts,
                                              int* __restrict__ cur,
                                              int2* __restrict__ sbuf,
                                              unsigned short* __restrict__ wppT) {
    __shared__ __align__(16) float smem[8192];   // 32 KB
    int b = blockIdx.x;
    int t = threadIdx.x;

    if (b < NB_SCORE) {
        // ---- per-node logit scalars rs[n][h], ts[n][h] (f32 exact; identical to R5) ----
        float* vrl = smem;            // 256 floats
        float* vtl = smem + 256;
        {
            int h = t >> 6, f = t & 63;
            const float* wrow = wproj + h * 4096 + f * 64;
            const float* rsp = rsc + h * 64;
            const float* tsp = tsc + h * 64;
            float ar = 0.f, at = 0.f;
            for (int g = 0; g < 64; ++g) {
                float w = wrow[g];
                ar += w * rsp[g];
                at += w * tsp[g];
            }
            vrl[t] = ar;
            vtl[t] = at;
        }
        __syncthreads();
        int n = b * 256 + t;
        if (n >= N_NODES) return;
        const float4* xr = (const float4*)(x + n * 64);
        float accr[4] = {0.f, 0.f, 0.f, 0.f};
        float acct[4] = {0.f, 0.f, 0.f, 0.f};
        for (int i = 0; i < 16; ++i) {
            float4 xv = xr[i];
#pragma unroll
            for (int h = 0; h < 4; ++h) {
                float4 a = ((const float4*)vrl)[h * 16 + i];
                accr[h] += xv.x * a.x + xv.y * a.y + xv.z * a.z + xv.w * a.w;
                float4 bb = ((const float4*)vtl)[h * 16 + i];
                acct[h] += xv.x * bb.x + xv.y * bb.y + xv.z * bb.z + xv.w * bb.w;
            }
        }
        ((float4*)rs)[n] = make_float4(accr[0], accr[1], accr[2], accr[3]);
        ((float4*)ts)[n] = make_float4(acct[0], acct[1], acct[2], acct[3]);
    } else if (b < NB_SCORE + NB_BUCKET) {
        // ---- bucket edges by receiver ----
        int e = (b - NB_SCORE) * 256 + t;
        if (e >= N_EDGES) return;
        int s = ei[e];
        int r = ei[N_EDGES + e];
        float len = el[e];
        int pos = atomicAdd(&cur[r], 1);
        if (pos < CAP) sbuf[r * CAP + pos] = make_int2(s, __float_as_int(len));
    } else {
        // ---- W'' precompute, one 64x64x64 f32 GEMM per task ----
        int k = b - NB_SCORE - NB_BUCKET;     // 0..8
        float* wo = smem;                     // wout [g][c]
        float* am = smem + 4096;              // A    [f][g]
        for (int i = 0; i < 16; ++i) wo[t + 256 * i] = wout[t + 256 * i];
        if (k < 8) {
            const float* M = (k < 4) ? (wrad + k * 4096) : (wtan + (k - 4) * 4096);
            for (int i = 0; i < 16; ++i) am[t + 256 * i] = M[t + 256 * i];
        } else {
            for (int i = 0; i < 16; ++i) {
                int e = t + 256 * i;
                float s = 0.f;
#pragma unroll
                for (int h = 0; h < 4; ++h) s += wrad[h * 4096 + e] + wtan[h * 4096 + e];
                am[e] = -s;
            }
        }
        __syncthreads();
        int c = t & 63;
        int fg = t >> 6;                      // 0..3
        for (int j = 0; j < 16; ++j) {
            int f = fg * 16 + j;
            float acc = 0.f;
            for (int g = 0; g < 64; ++g) acc += am[f * 64 + g] * wo[g * 64 + c];
            wppT[c * 576 + k * 64 + f] = f2bf(acc * 0.25f);
        }
    }
}

// ---------- D2: softmax + alpha-weighted x-sums + fused output GEMM (MFMA) ----------
// Block = 16 nodes (4 per wave). Stage A: per-node alpha + V-row accumulation into
// LDS (bf16). Stage B: dense [16 x 576] @ W''T -> out tile via MFMA.
__global__ void __launch_bounds__(256) k_node(const int* __restrict__ cur,
                                              const int2* __restrict__ sbuf,
                                              const float* __restrict__ rs,
                                              const float* __restrict__ ts,
                                              const float* __restrict__ rdls,
                                              const float* __restrict__ tb,
                                              const float* __restrict__ tw,
                                              const float* __restrict__ x,
                                              const unsigned short* __restrict__ wppT,
                                              float* __restrict__ out) {
    __shared__ __align__(16) unsigned short accL[16 * 584];   // 18688 B, row stride 584 (2-way-free banks)
    __shared__ __align__(16) float aldsb[4][CAP * 8];         // 8192 B
    __shared__ int sldsb[4][CAP];                             // 1024 B
    int t = threadIdx.x;
    int wid = t >> 6, lane = t & 63;
    int blk = blockIdx.x;

    float scale = softplus_f(rdls[0]);
    float tb0 = tb[0], tb1 = tb[1], tb2 = tb[2], tb3 = tb[3];
    float tw0 = tw[0], tw1 = tw[1], tw2 = tw[2], tw3 = tw[3];
    float* alds = aldsb[wid];
    int*   slds = sldsb[wid];

    for (int j = 0; j < 4; ++j) {
        int n = blk * 16 + wid * 4 + j;
        int row = wid * 4 + j;
        int deg = min(cur[n], CAP);

        float4 rsr = ((const float4*)rs)[n];
        float4 tsr = ((const float4*)ts)[n];

        const float NEG = -3.402823466e38f;
        float rl0 = NEG, rl1 = NEG, rl2 = NEG, rl3 = NEG;
        float tl0 = NEG, tl1 = NEG, tl2 = NEG, tl3 = NEG;
        int s_e = 0;
        if (lane < deg) {
            int2 sl = sbuf[n * CAP + lane];
            s_e = sl.x;
            float len = __int_as_float(sl.y);
            float4 rss = ((const float4*)rs)[s_e];
            float4 tss = ((const float4*)ts)[s_e];
            float sl0 = scale * len;
            float i0 = 1.f / (softplus_f(tb0 + tw0 * len) + 1e-4f);
            float i1 = 1.f / (softplus_f(tb1 + tw1 * len) + 1e-4f);
            float i2 = 1.f / (softplus_f(tb2 + tw2 * len) + 1e-4f);
            float i3 = 1.f / (softplus_f(tb3 + tw3 * len) + 1e-4f);
            rl0 = ((rss.x - rsr.x) - sl0) * i0;
            rl1 = ((rss.y - rsr.y) - sl0) * i1;
            rl2 = ((rss.z - rsr.z) - sl0) * i2;
            rl3 = ((rss.w - rsr.w) - sl0) * i3;
            tl0 = tss.x - tsr.x;
            tl1 = tss.y - tsr.y;
            tl2 = tss.z - tsr.z;
            tl3 = tss.w - tsr.w;
        }
        float mr0 = rl0, mr1 = rl1, mr2 = rl2, mr3 = rl3;
        float mt0 = tl0, mt1 = tl1, mt2 = tl2, mt3 = tl3;
#pragma unroll
        for (int d = 32; d >= 1; d >>= 1) {
            mr0 = fmaxf(mr0, __shfl_xor(mr0, d)); mr1 = fmaxf(mr1, __shfl_xor(mr1, d));
            mr2 = fmaxf(mr2, __shfl_xor(mr2, d)); mr3 = fmaxf(mr3, __shfl_xor(mr3, d));
            mt0 = fmaxf(mt0, __shfl_xor(mt0, d)); mt1 = fmaxf(mt1, __shfl_xor(mt1, d));
            mt2 = fmaxf(mt2, __shfl_xor(mt2, d)); mt3 = fmaxf(mt3, __shfl_xor(mt3, d));
        }
        float er0 = 0.f, er1 = 0.f, er2 = 0.f, er3 = 0.f;
        float et0 = 0.f, et1 = 0.f, et2 = 0.f, et3 = 0.f;
        if (lane < deg) {
            er0 = expf(rl0 - mr0); er1 = expf(rl1 - mr1);
            er2 = expf(rl2 - mr2); er3 = expf(rl3 - mr3);
            et0 = expf(tl0 - mt0); et1 = expf(tl1 - mt1);
            et2 = expf(tl2 - mt2); et3 = expf(tl3 - mt3);
        }
        float sr0 = er0, sr1 = er1, sr2 = er2, sr3 = er3;
        float st0 = et0, st1 = et1, st2 = et2, st3 = et3;
#pragma unroll
        for (int d = 32; d >= 1; d >>= 1) {
            sr0 += __shfl_xor(sr0, d); sr1 += __shfl_xor(sr1, d);
            sr2 += __shfl_xor(sr2, d); sr3 += __shfl_xor(sr3, d);
            st0 += __shfl_xor(st0, d); st1 += __shfl_xor(st1, d);
            st2 += __shfl_xor(st2, d); st3 += __shfl_xor(st3, d);
        }
        if (lane < deg) {
            float* ap = alds + lane * 8;
            ((float4*)ap)[0] = make_float4(er0 / sr0, er1 / sr1, er2 / sr2, er3 / sr3);
            ((float4*)ap)[1] = make_float4(et0 / st0, et1 / st1, et2 / st2, et3 / st3);
            slds[lane] = s_e;
        }

        // ---- accumulate V row: lane = feature f; 9 accumulators ----
        float a0 = 0.f, a1 = 0.f, a2 = 0.f, a3 = 0.f;
        float b0 = 0.f, b1 = 0.f, b2 = 0.f, b3 = 0.f;
        int i = 0;
        for (; i + 2 <= deg; i += 2) {
            int s0 = slds[i], s1 = slds[i + 1];
            float4 ar0 = ((const float4*)(alds + i * 8))[0];
            float4 at0 = ((const float4*)(alds + i * 8))[1];
            float4 ar1 = ((const float4*)(alds + (i + 1) * 8))[0];
            float4 at1 = ((const float4*)(alds + (i + 1) * 8))[1];
            float xv0 = x[s0 * 64 + lane];
            float xv1 = x[s1 * 64 + lane];
            a0 += ar0.x * xv0 + ar1.x * xv1;
            a1 += ar0.y * xv0 + ar1.y * xv1;
            a2 += ar0.z * xv0 + ar1.z * xv1;
            a3 += ar0.w * xv0 + ar1.w * xv1;
            b0 += at0.x * xv0 + at1.x * xv1;
            b1 += at0.y * xv0 + at1.y * xv1;
            b2 += at0.z * xv0 + at1.z * xv1;
            b3 += at0.w * xv0 + at1.w * xv1;
        }
        if (i < deg) {
            int s0 = slds[i];
            float4 ar0 = ((const float4*)(alds + i * 8))[0];
            float4 at0 = ((const float4*)(alds + i * 8))[1];
            float xv0 = x[s0 * 64 + lane];
            a0 += ar0.x * xv0; a1 += ar0.y * xv0; a2 += ar0.z * xv0; a3 += ar0.w * xv0;
            b0 += at0.x * xv0; b1 += at0.y * xv0; b2 += at0.z * xv0; b3 += at0.w * xv0;
        }
        float c8 = (deg > 0) ? x[n * 64 + lane] : 0.f;   // receiver slot (sign folded into W''_8)

        unsigned short* arow = accL + row * 584;
        arow[0 * 64 + lane] = f2bf(a0);
        arow[1 * 64 + lane] = f2bf(a1);
        arow[2 * 64 + lane] = f2bf(a2);
        arow[3 * 64 + lane] = f2bf(a3);
        arow[4 * 64 + lane] = f2bf(b0);
        arow[5 * 64 + lane] = f2bf(b1);
        arow[6 * 64 + lane] = f2bf(b2);
        arow[7 * 64 + lane] = f2bf(b3);
        arow[8 * 64 + lane] = f2bf(c8);
    }
    __syncthreads();

    // ---- stage B: [16 x 576] @ W''T -> out[16 x 64]; wave wid does cols 16*wid.. ----
    int c = lane & 15, q = lane >> 4;
    f32x4 dacc = {0.f, 0.f, 0.f, 0.f};
    const unsigned short* bp = wppT + (16 * wid + c) * 576 + q * 8;
    const unsigned short* ap = accL + c * 584 + q * 8;   // A: lane&15 = m (node row)
#pragma unroll
    for (int kc = 0; kc < 18; ++kc) {
        bf16x8 af = *(const bf16x8*)(ap + kc * 32);
        bf16x8 bf = *(const bf16x8*)(bp + kc * 32);
        dacc = __builtin_amdgcn_mfma_f32_16x16x32_bf16(af, bf, dacc, 0, 0, 0);
    }
#pragma unroll
    for (int r = 0; r < 4; ++r) {
        int node = blk * 16 + q * 4 + r;
        int col = 16 * wid + c;
        out[node * 64 + col] = x[node * 64 + col] + dacc[r];
    }
}

extern "C" void kernel_launch(void* const* d_in, const int* in_sizes, int n_in,
                              void* d_out, int out_size, void* d_ws, size_t ws_size,
                              hipStream_t stream) {
    const float* x     = (const float*)d_in[0];
    const int*   ei    = (const int*)d_in[1];
    /* d_in[2] edge_vec unused by reference */
    const float* el    = (const float*)d_in[3];
    const float* wproj = (const float*)d_in[4];
    const float* wrad  = (const float*)d_in[5];
    const float* wtan  = (const float*)d_in[6];
    const float* rsc   = (const float*)d_in[7];
    const float* tsc   = (const float*)d_in[8];
    const float* rdls  = (const float*)d_in[9];
    const float* tb    = (const float*)d_in[10];
    const float* tw    = (const float*)d_in[11];
    const float* wout  = (const float*)d_in[12];
    float* out = (float*)d_out;

    char* w = (char*)d_ws;
    size_t o = 0;
    auto nxt = [&](size_t bytes) -> char* {
        char* p = w + o;
        o += (bytes + 255) & ~(size_t)255;
        return p;
    };
    float* rs = (float*)nxt((size_t)N_NODES * 4 * 4);
    float* ts = (float*)nxt((size_t)N_NODES * 4 * 4);
    int*   cur = (int*)nxt((size_t)N_NODES * 4);
    int2*  sbuf = (int2*)nxt((size_t)N_NODES * CAP * 8);
    unsigned short* wppT = (unsigned short*)nxt((size_t)64 * 576 * 2);

    hipMemsetAsync(cur, 0, (size_t)N_NODES * 4, stream);

    k_prep<<<NB_D1, 256, 0, stream>>>(x, wproj, wrad, wtan, rsc, tsc, wout,
                                      ei, el, rs, ts, cur, sbuf, wppT);
    k_node<<<625, 256, 0, stream>>>(cur, sbuf, rs, ts, rdls, tb, tw, x, wppT, out);
}

// Round 7
// 127.091 us; speedup vs baseline: 2.6194x; 1.0816x over previous
//
#include <hip/hip_runtime.h>
#include <math.h>

#define N_NODES 10000
#define N_EDGES 160000
#define CAP 64

// D1 task split
#define NB_SCORE 40
#define NB_BUCKET 625
#define NB_WPP 9
#define NB_D1 (NB_SCORE + NB_BUCKET + NB_WPP)

typedef short bf16x8 __attribute__((ext_vector_type(8)));
typedef float f32x4 __attribute__((ext_vector_type(4)));

// ---------- helpers ----------
__device__ __forceinline__ float bf2f(unsigned short u) {
    return __uint_as_float(((unsigned int)u) << 16);
}
__device__ __forceinline__ unsigned short f2bf(float f) {
    unsigned int x = __float_as_uint(f);
    unsigned int r = (x + 0x7fffu + ((x >> 16) & 1u)) >> 16;   // RNE
    return (unsigned short)r;
}
__device__ __forceinline__ float softplus_f(float x) {
    return fmaxf(x, 0.f) + log1pf(expf(-fabsf(x)));
}

// ---------- D1: scores | bucket | W'' precompute ----------
// W''_k = Wk @ Wout * 0.25 (k=0..3: Wr[h]; k=4..7: Wt[h]; k=8: -sum of all 8),
// stored TRANSPOSED: wppT[c*576 + k*64 + f] (bf16), c = out column.
__global__ void __launch_bounds__(256) k_prep(const float* __restrict__ x,
                                              const float* __restrict__ wproj,
                                              const float* __restrict__ wrad,
                                              const float* __restrict__ wtan,
                                              const float* __restrict__ rsc,
                                              const float* __restrict__ tsc,
                                              const float* __restrict__ wout,
                                              const int* __restrict__ ei,
                                              const float* __restrict__ el,
                                              float* __restrict__ rs,
                                              float* __restrict__ ts,
                                              int* __restrict__ cur,
                                              int2* __restrict__ sbuf,
                                              unsigned short* __restrict__ wppT) {
    __shared__ __align__(16) float smem[8192];   // 32 KB
    int b = blockIdx.x;
    int t = threadIdx.x;

    if (b < NB_SCORE) {
        // ---- per-node logit scalars rs[n][h], ts[n][h] (f32 exact path) ----
        float* vrl = smem;            // 256 floats
        float* vtl = smem + 256;
        {
            int h = t >> 6, f = t & 63;
            const float* wrow = wproj + h * 4096 + f * 64;
            const float* rsp = rsc + h * 64;
            const float* tsp = tsc + h * 64;
            float ar = 0.f, at = 0.f;
            for (int g = 0; g < 64; ++g) {
                float w = wrow[g];
                ar += w * rsp[g];
                at += w * tsp[g];
            }
            vrl[t] = ar;
            vtl[t] = at;
        }
        __syncthreads();
        int n = b * 256 + t;
        if (n >= N_NODES) return;
        const float4* xr = (const float4*)(x + n * 64);
        float accr[4] = {0.f, 0.f, 0.f, 0.f};
        float acct[4] = {0.f, 0.f, 0.f, 0.f};
        for (int i = 0; i < 16; ++i) {
            float4 xv = xr[i];
#pragma unroll
            for (int h = 0; h < 4; ++h) {
                float4 a = ((const float4*)vrl)[h * 16 + i];
                accr[h] += xv.x * a.x + xv.y * a.y + xv.z * a.z + xv.w * a.w;
                float4 bb = ((const float4*)vtl)[h * 16 + i];
                acct[h] += xv.x * bb.x + xv.y * bb.y + xv.z * bb.z + xv.w * bb.w;
            }
        }
        ((float4*)rs)[n] = make_float4(accr[0], accr[1], accr[2], accr[3]);
        ((float4*)ts)[n] = make_float4(acct[0], acct[1], acct[2], acct[3]);
    } else if (b < NB_SCORE + NB_BUCKET) {
        // ---- bucket edges by receiver ----
        int e = (b - NB_SCORE) * 256 + t;
        if (e >= N_EDGES) return;
        int s = ei[e];
        int r = ei[N_EDGES + e];
        float len = el[e];
        int pos = atomicAdd(&cur[r], 1);
        if (pos < CAP) sbuf[r * CAP + pos] = make_int2(s, __float_as_int(len));
    } else {
        // ---- W'' precompute, one 64x64x64 f32 GEMM per task ----
        int k = b - NB_SCORE - NB_BUCKET;     // 0..8
        float* wo = smem;                     // wout [g][c]
        float* am = smem + 4096;              // A    [f][g]
        for (int i = 0; i < 16; ++i) wo[t + 256 * i] = wout[t + 256 * i];
        if (k < 8) {
            const float* M = (k < 4) ? (wrad + k * 4096) : (wtan + (k - 4) * 4096);
            for (int i = 0; i < 16; ++i) am[t + 256 * i] = M[t + 256 * i];
        } else {
            for (int i = 0; i < 16; ++i) {
                int e = t + 256 * i;
                float s = 0.f;
#pragma unroll
                for (int h = 0; h < 4; ++h) s += wrad[h * 4096 + e] + wtan[h * 4096 + e];
                am[e] = -s;
            }
        }
        __syncthreads();
        int c = t & 63;
        int fg = t >> 6;                      // 0..3
        for (int j = 0; j < 16; ++j) {
            int f = fg * 16 + j;
            float acc = 0.f;
            for (int g = 0; g < 64; ++g) acc += am[f * 64 + g] * wo[g * 64 + c];
            wppT[c * 576 + k * 64 + f] = f2bf(acc * 0.25f);
        }
    }
}

// ---------- D2: softmax + alpha-weighted x-sums + fused output GEMM (MFMA) ----------
// Block = 1024 threads = 16 waves = 16 nodes (1 node/wave for latency hiding).
// Stage A: per-node alpha + V-row accumulation into LDS (bf16).
// Stage B: dense [16 x 576] @ W''T -> out tile via MFMA (waves 0..3).
__global__ void __launch_bounds__(1024, 8) k_node(const int* __restrict__ cur,
                                                  const int2* __restrict__ sbuf,
                                                  const float* __restrict__ rs,
                                                  const float* __restrict__ ts,
                                                  const float* __restrict__ rdls,
                                                  const float* __restrict__ tb,
                                                  const float* __restrict__ tw,
                                                  const float* __restrict__ x,
                                                  const unsigned short* __restrict__ wppT,
                                                  float* __restrict__ out) {
    __shared__ __align__(16) unsigned short accL[16 * 584];   // 18688 B
    __shared__ __align__(16) float aldsb[16][CAP * 8];        // 32768 B
    __shared__ int sldsb[16][CAP];                            // 4096 B
    int t = threadIdx.x;
    int wid = t >> 6, lane = t & 63;
    int blk = blockIdx.x;

    float scale = softplus_f(rdls[0]);
    float tb0 = tb[0], tb1 = tb[1], tb2 = tb[2], tb3 = tb[3];
    float tw0 = tw[0], tw1 = tw[1], tw2 = tw[2], tw3 = tw[3];
    float* alds = aldsb[wid];
    int*   slds = sldsb[wid];

    int n = blk * 16 + wid;                   // 625*16 == N_NODES exactly
    int deg = min(cur[n], CAP);

    float4 rsr = ((const float4*)rs)[n];
    float4 tsr = ((const float4*)ts)[n];

    const float NEG = -3.402823466e38f;
    float rl0 = NEG, rl1 = NEG, rl2 = NEG, rl3 = NEG;
    float tl0 = NEG, tl1 = NEG, tl2 = NEG, tl3 = NEG;
    int s_e = 0;
    if (lane < deg) {
        int2 sl = sbuf[n * CAP + lane];
        s_e = sl.x;
        float len = __int_as_float(sl.y);
        float4 rss = ((const float4*)rs)[s_e];
        float4 tss = ((const float4*)ts)[s_e];
        float sl0 = scale * len;
        float i0 = 1.f / (softplus_f(tb0 + tw0 * len) + 1e-4f);
        float i1 = 1.f / (softplus_f(tb1 + tw1 * len) + 1e-4f);
        float i2 = 1.f / (softplus_f(tb2 + tw2 * len) + 1e-4f);
        float i3 = 1.f / (softplus_f(tb3 + tw3 * len) + 1e-4f);
        rl0 = ((rss.x - rsr.x) - sl0) * i0;
        rl1 = ((rss.y - rsr.y) - sl0) * i1;
        rl2 = ((rss.z - rsr.z) - sl0) * i2;
        rl3 = ((rss.w - rsr.w) - sl0) * i3;
        tl0 = tss.x - tsr.x;
        tl1 = tss.y - tsr.y;
        tl2 = tss.z - tsr.z;
        tl3 = tss.w - tsr.w;
    }
    float mr0 = rl0, mr1 = rl1, mr2 = rl2, mr3 = rl3;
    float mt0 = tl0, mt1 = tl1, mt2 = tl2, mt3 = tl3;
#pragma unroll
    for (int d = 32; d >= 1; d >>= 1) {
        mr0 = fmaxf(mr0, __shfl_xor(mr0, d)); mr1 = fmaxf(mr1, __shfl_xor(mr1, d));
        mr2 = fmaxf(mr2, __shfl_xor(mr2, d)); mr3 = fmaxf(mr3, __shfl_xor(mr3, d));
        mt0 = fmaxf(mt0, __shfl_xor(mt0, d)); mt1 = fmaxf(mt1, __shfl_xor(mt1, d));
        mt2 = fmaxf(mt2, __shfl_xor(mt2, d)); mt3 = fmaxf(mt3, __shfl_xor(mt3, d));
    }
    float er0 = 0.f, er1 = 0.f, er2 = 0.f, er3 = 0.f;
    float et0 = 0.f, et1 = 0.f, et2 = 0.f, et3 = 0.f;
    if (lane < deg) {
        er0 = expf(rl0 - mr0); er1 = expf(rl1 - mr1);
        er2 = expf(rl2 - mr2); er3 = expf(rl3 - mr3);
        et0 = expf(tl0 - mt0); et1 = expf(tl1 - mt1);
        et2 = expf(tl2 - mt2); et3 = expf(tl3 - mt3);
    }
    float sr0 = er0, sr1 = er1, sr2 = er2, sr3 = er3;
    float st0 = et0, st1 = et1, st2 = et2, st3 = et3;
#pragma unroll
    for (int d = 32; d >= 1; d >>= 1) {
        sr0 += __shfl_xor(sr0, d); sr1 += __shfl_xor(sr1, d);
        sr2 += __shfl_xor(sr2, d); sr3 += __shfl_xor(sr3, d);
        st0 += __shfl_xor(st0, d); st1 += __shfl_xor(st1, d);
        st2 += __shfl_xor(st2, d); st3 += __shfl_xor(st3, d);
    }
    if (lane < deg) {
        float* ap = alds + lane * 8;
        ((float4*)ap)[0] = make_float4(er0 / sr0, er1 / sr1, er2 / sr2, er3 / sr3);
        ((float4*)ap)[1] = make_float4(et0 / st0, et1 / st1, et2 / st2, et3 / st3);
        slds[lane] = s_e;
    }

    // ---- accumulate V row: lane = feature f; 9 accumulators; 4-way unrolled ----
    float a0 = 0.f, a1 = 0.f, a2 = 0.f, a3 = 0.f;
    float b0 = 0.f, b1 = 0.f, b2 = 0.f, b3 = 0.f;
    int i = 0;
    for (; i + 4 <= deg; i += 4) {
        int s0 = slds[i], s1 = slds[i + 1], s2 = slds[i + 2], s3 = slds[i + 3];
        float xv0 = x[s0 * 64 + lane];
        float xv1 = x[s1 * 64 + lane];
        float xv2 = x[s2 * 64 + lane];
        float xv3 = x[s3 * 64 + lane];
        float4 ar0 = ((const float4*)(alds + i * 8))[0];
        float4 at0 = ((const float4*)(alds + i * 8))[1];
        float4 ar1 = ((const float4*)(alds + (i + 1) * 8))[0];
        float4 at1 = ((const float4*)(alds + (i + 1) * 8))[1];
        float4 ar2 = ((const float4*)(alds + (i + 2) * 8))[0];
        float4 at2 = ((const float4*)(alds + (i + 2) * 8))[1];
        float4 ar3 = ((const float4*)(alds + (i + 3) * 8))[0];
        float4 at3 = ((const float4*)(alds + (i + 3) * 8))[1];
        a0 += ar0.x * xv0 + ar1.x * xv1 + ar2.x * xv2 + ar3.x * xv3;
        a1 += ar0.y * xv0 + ar1.y * xv1 + ar2.y * xv2 + ar3.y * xv3;
        a2 += ar0.z * xv0 + ar1.z * xv1 + ar2.z * xv2 + ar3.z * xv3;
        a3 += ar0.w * xv0 + ar1.w * xv1 + ar2.w * xv2 + ar3.w * xv3;
        b0 += at0.x * xv0 + at1.x * xv1 + at2.x * xv2 + at3.x * xv3;
        b1 += at0.y * xv0 + at1.y * xv1 + at2.y * xv2 + at3.y * xv3;
        b2 += at0.z * xv0 + at1.z * xv1 + at2.z * xv2 + at3.z * xv3;
        b3 += at0.w * xv0 + at1.w * xv1 + at2.w * xv2 + at3.w * xv3;
    }
    for (; i < deg; ++i) {
        int s0 = slds[i];
        float xv0 = x[s0 * 64 + lane];
        float4 ar0 = ((const float4*)(alds + i * 8))[0];
        float4 at0 = ((const float4*)(alds + i * 8))[1];
        a0 += ar0.x * xv0; a1 += ar0.y * xv0; a2 += ar0.z * xv0; a3 += ar0.w * xv0;
        b0 += at0.x * xv0; b1 += at0.y * xv0; b2 += at0.z * xv0; b3 += at0.w * xv0;
    }
    float c8 = (deg > 0) ? x[n * 64 + lane] : 0.f;   // receiver slot (sign in W''_8)

    unsigned short* arow = accL + wid * 584;
    arow[0 * 64 + lane] = f2bf(a0);
    arow[1 * 64 + lane] = f2bf(a1);
    arow[2 * 64 + lane] = f2bf(a2);
    arow[3 * 64 + lane] = f2bf(a3);
    arow[4 * 64 + lane] = f2bf(b0);
    arow[5 * 64 + lane] = f2bf(b1);
    arow[6 * 64 + lane] = f2bf(b2);
    arow[7 * 64 + lane] = f2bf(b3);
    arow[8 * 64 + lane] = f2bf(c8);
    __syncthreads();

    // ---- stage B: [16 x 576] @ W''T -> out[16 x 64]; waves 0..3 ----
    if (wid < 4) {
        int c = lane & 15, q = lane >> 4;
        f32x4 dacc = {0.f, 0.f, 0.f, 0.f};
        const unsigned short* bp = wppT + (16 * wid + c) * 576 + q * 8;
        const unsigned short* ap = accL + c * 584 + q * 8;   // A: m = lane&15 (node row)
#pragma unroll
        for (int kc = 0; kc < 18; ++kc) {
            bf16x8 af = *(const bf16x8*)(ap + kc * 32);
            bf16x8 bf = *(const bf16x8*)(bp + kc * 32);
            dacc = __builtin_amdgcn_mfma_f32_16x16x32_bf16(af, bf, dacc, 0, 0, 0);
        }
#pragma unroll
        for (int r = 0; r < 4; ++r) {
            int node = blk * 16 + q * 4 + r;
            int col = 16 * wid + c;
            out[node * 64 + col] = x[node * 64 + col] + dacc[r];
        }
    }
}

extern "C" void kernel_launch(void* const* d_in, const int* in_sizes, int n_in,
                              void* d_out, int out_size, void* d_ws, size_t ws_size,
                              hipStream_t stream) {
    const float* x     = (const float*)d_in[0];
    const int*   ei    = (const int*)d_in[1];
    /* d_in[2] edge_vec unused by reference */
    const float* el    = (const float*)d_in[3];
    const float* wproj = (const float*)d_in[4];
    const float* wrad  = (const float*)d_in[5];
    const float* wtan  = (const float*)d_in[6];
    const float* rsc   = (const float*)d_in[7];
    const float* tsc   = (const float*)d_in[8];
    const float* rdls  = (const float*)d_in[9];
    const float* tb    = (const float*)d_in[10];
    const float* tw    = (const float*)d_in[11];
    const float* wout  = (const float*)d_in[12];
    float* out = (float*)d_out;

    char* w = (char*)d_ws;
    size_t o = 0;
    auto nxt = [&](size_t bytes) -> char* {
        char* p = w + o;
        o += (bytes + 255) & ~(size_t)255;
        return p;
    };
    float* rs = (float*)nxt((size_t)N_NODES * 4 * 4);
    float* ts = (float*)nxt((size_t)N_NODES * 4 * 4);
    int*   cur = (int*)nxt((size_t)N_NODES * 4);
    int2*  sbuf = (int2*)nxt((size_t)N_NODES * CAP * 8);
    unsigned short* wppT = (unsigned short*)nxt((size_t)64 * 576 * 2);

    hipMemsetAsync(cur, 0, (size_t)N_NODES * 4, stream);

    k_prep<<<NB_D1, 256, 0, stream>>>(x, wproj, wrad, wtan, rsc, tsc, wout,
                                      ei, el, rs, ts, cur, sbuf, wppT);
    k_node<<<625, 1024, 0, stream>>>(cur, sbuf, rs, ts, rdls, tb, tw, x, wppT, out);
}